// Round 1
// baseline (11836.142 us; speedup 1.0000x reference)
//
#include <hip/hip_runtime.h>
#include <math.h>

#define MU_F 0.1f
#define SHRINK_F 0.01f   // LMBD * MU
#define BN_EPS_F 1e-5f

// ---------------------------------------------------------------------------
// Unified implicit-GEMM direct conv.
//   MODE 0: forward conv, stride S, pad PAD.        out[oh] <- in[oh*S-PAD+kh]
//   MODE 1: transposed conv stride 1 (pad 1).       out[ih] <- in[ih+PAD-kh]
//   MODE 2: transposed conv stride 2 (pad 1, output_padding 1), quadrant-parity
//           pixel mapping: blockIdx.x = q*ptiles + tile, q in [0,4) selects the
//           output-pixel parity class (eh,ew) so tap validity is block-uniform
//           and invalid taps are skipped wholesale (no zero-multiply waste).
// Weight address = co*wso + cred*wsr + (kh*KS+kw)  (handles both W and W^T use)
// Epilogue: v = alpha*acc + beta*aux1[g] + delta; if(relu1) relu;
//           if(pscale) v = pscale[co]*v + pbias[co]; if(aux3) v += aux3[g];
//           if(relu2) relu.   Covers: shrink, r = x - convT, BN-fold, final add.
// Tile: 64 out-channels x 64 pixels per block, 256 threads, 4x4 per thread.
// ---------------------------------------------------------------------------
template<int KS, int S, int PAD, int MODE>
__global__ __launch_bounds__(256)
void conv_gemm(const float* __restrict__ in, const float* __restrict__ wt,
               float* __restrict__ out,
               int Cred, int Cout, int Hin, int Win, int Hout, int Wout,
               int wso, int wsr, int ptiles,
               float alpha, const float* __restrict__ aux1, float beta,
               float delta, int relu1,
               const float* __restrict__ pscale, const float* __restrict__ pbias,
               const float* __restrict__ aux3, int relu2)
{
    __shared__ float Ws[16][64];
    __shared__ float Xs[16][68];   // 68*4B = 272B row stride, 16B aligned

    const int tid = threadIdx.x;
    const int tx = tid & 15, ty = tid >> 4;
    const int n = blockIdx.z;
    const int co0 = blockIdx.y * 64;

    int eh = 0, ew = 0, p0;
    if (MODE == 2) {
        int q = blockIdx.x / ptiles;
        p0 = (blockIdx.x - q * ptiles) * 64;
        eh = q >> 1; ew = q & 1;
    } else {
        p0 = blockIdx.x * 64;
    }

    const int HWo = Hout * Wout;
    const int QW  = Wout >> 1;
    const int PHW = (MODE == 2) ? (Hout >> 1) * QW : HWo;  // pixel-domain size

    // hoist staged-pixel decode (each thread stages 4 X elements / chunk)
    int sp_ph[4], sp_pw[4], sp_pl[4];
    bool sp_ok[4];
#pragma unroll
    for (int i = 0; i < 4; ++i) {
        int idx = i * 256 + tid;
        int pl = idx & 63;
        sp_pl[i] = pl;
        int p = p0 + pl;
        sp_ok[i] = (p < PHW);
        int w = (MODE == 2) ? QW : Wout;
        int ph = p / w;
        sp_ph[i] = ph; sp_pw[i] = p - ph * w;
    }

    float acc[4][4] = {};
    const size_t in_n = (size_t)n * Cred * Hin * Win;

    for (int kh = 0; kh < KS; ++kh) {
        for (int kw = 0; kw < KS; ++kw) {
            if (MODE == 2) {
                // tap parity must match pixel parity class (uniform per block)
                if ((((kh ^ (eh + 1)) & 1) != 0) || (((kw ^ (ew + 1)) & 1) != 0))
                    continue;
            }
            const int tap = kh * KS + kw;
            for (int c0 = 0; c0 < Cred; c0 += 16) {
#pragma unroll
                for (int i = 0; i < 4; ++i) {
                    int idx = i * 256 + tid;
                    int kc = idx >> 6, cl = idx & 63;
                    Ws[kc][cl] = wt[(size_t)(co0 + cl) * wso + (size_t)(c0 + kc) * wsr + tap];
                }
#pragma unroll
                for (int i = 0; i < 4; ++i) {
                    int idx = i * 256 + tid;
                    int kc = idx >> 6;
                    float v = 0.f;
                    if (sp_ok[i]) {
                        int ihh, iww; bool ok;
                        if (MODE == 0) {
                            ihh = sp_ph[i] * S - PAD + kh;
                            iww = sp_pw[i] * S - PAD + kw;
                            ok = (unsigned)ihh < (unsigned)Hin && (unsigned)iww < (unsigned)Win;
                        } else if (MODE == 1) {
                            ihh = sp_ph[i] + PAD - kh;
                            iww = sp_pw[i] + PAD - kw;
                            ok = (unsigned)ihh < (unsigned)Hin && (unsigned)iww < (unsigned)Win;
                        } else {
                            int ih = 2 * sp_ph[i] + eh, iw = 2 * sp_pw[i] + ew;
                            int nh = ih + PAD - kh, nw = iw + PAD - kw; // even by parity
                            ihh = nh >> 1; iww = nw >> 1;
                            ok = nh >= 0 && nw >= 0 && ihh < Hin && iww < Win;
                        }
                        if (ok) v = in[in_n + ((size_t)(c0 + kc) * Hin + ihh) * Win + iww];
                    }
                    Xs[kc][sp_pl[i]] = v;
                }
                __syncthreads();
#pragma unroll
                for (int k = 0; k < 16; ++k) {
                    float4 wv = *(const float4*)&Ws[k][ty * 4];
                    float4 xv = *(const float4*)&Xs[k][tx * 4];
                    acc[0][0] += wv.x * xv.x; acc[0][1] += wv.x * xv.y;
                    acc[0][2] += wv.x * xv.z; acc[0][3] += wv.x * xv.w;
                    acc[1][0] += wv.y * xv.x; acc[1][1] += wv.y * xv.y;
                    acc[1][2] += wv.y * xv.z; acc[1][3] += wv.y * xv.w;
                    acc[2][0] += wv.z * xv.x; acc[2][1] += wv.z * xv.y;
                    acc[2][2] += wv.z * xv.z; acc[2][3] += wv.z * xv.w;
                    acc[3][0] += wv.w * xv.x; acc[3][1] += wv.w * xv.y;
                    acc[3][2] += wv.w * xv.z; acc[3][3] += wv.w * xv.w;
                }
                __syncthreads();
            }
        }
    }

    // epilogue
#pragma unroll
    for (int i = 0; i < 4; ++i) {
        int co = co0 + ty * 4 + i;
        float ps = 1.f, pb = 0.f;
        if (pscale) { ps = pscale[co]; pb = pbias[co]; }
#pragma unroll
        for (int j = 0; j < 4; ++j) {
            int p = p0 + tx * 4 + j;
            if (p >= PHW) continue;
            size_t g;
            if (MODE == 2) {
                int ph = p / QW, pw = p - (p / QW) * QW;
                int ih = 2 * ph + eh, iw = 2 * pw + ew;
                g = (((size_t)n * Cout + co) * Hout + ih) * Wout + iw;
            } else {
                g = ((size_t)n * Cout + co) * HWo + p;
            }
            float v = alpha * acc[i][j] + delta;
            if (aux1) v += beta * aux1[g];
            if (relu1) v = fmaxf(v, 0.f);
            if (pscale) v = ps * v + pb;
            if (aux3) v += aux3[g];
            if (relu2) v = fmaxf(v, 0.f);
            out[g] = v;
        }
    }
}

// a = w1*c + w2*c_pre   (FISTA momentum combine), float4 vectorized
__global__ __launch_bounds__(256)
void comb_kernel(const float* __restrict__ c, const float* __restrict__ p,
                 float* __restrict__ a, float w1, float w2, int n4)
{
    int i = blockIdx.x * 256 + threadIdx.x;
    if (i < n4) {
        float4 cv = ((const float4*)c)[i];
        float4 pv = ((const float4*)p)[i];
        float4 r;
        r.x = w1 * cv.x + w2 * pv.x; r.y = w1 * cv.y + w2 * pv.y;
        r.z = w1 * cv.z + w2 * pv.z; r.w = w1 * cv.w + w2 * pv.w;
        ((float4*)a)[i] = r;
    }
}

// per-filter unit L2 norm: Wn[co,:] = W[co,:] / (||W[co,:]|| + 1e-12)
__global__ __launch_bounds__(256)
void norm_w_kernel(const float* __restrict__ W, float* __restrict__ Wn, int CK)
{
    __shared__ float red[256];
    int co = blockIdx.x, tid = threadIdx.x;
    const float* w = W + (size_t)co * CK;
    float s = 0.f;
    for (int i = tid; i < CK; i += 256) { float v = w[i]; s += v * v; }
    red[tid] = s; __syncthreads();
    for (int o = 128; o > 0; o >>= 1) {
        if (tid < o) red[tid] += red[tid + o];
        __syncthreads();
    }
    float inv = 1.f / (sqrtf(red[0]) + 1e-12f);
    for (int i = tid; i < CK; i += 256) Wn[(size_t)co * CK + i] = w[i] * inv;
}

// eval-mode BN folded to scale/shift: s = g*rsqrt(v+eps), t = b - m*s
__global__ __launch_bounds__(256)
void bn_prep_kernel(const float* __restrict__ g, const float* __restrict__ b,
                    const float* __restrict__ m, const float* __restrict__ v,
                    float* __restrict__ s, float* __restrict__ t, int C)
{
    int i = blockIdx.x * 256 + threadIdx.x;
    if (i < C) {
        float sc = g[i] * rsqrtf(v[i] + BN_EPS_F);
        s[i] = sc; t[i] = b[i] - m[i] * sc;
    }
}

extern "C" void kernel_launch(void* const* d_in, const int* in_sizes, int n_in,
                              void* d_out, int out_size, void* d_ws, size_t ws_size,
                              hipStream_t stream)
{
    const float* x    = (const float*)d_in[0];   // (32,128,56,56)
    const float* W1   = (const float*)d_in[1];   // (256,128,3,3)
    const float* W2   = (const float*)d_in[2];   // (256,256,3,3)
    const float* Wsc  = (const float*)d_in[3];   // (256,128,1,1)
    const float* bn1g = (const float*)d_in[4];
    const float* bn1b = (const float*)d_in[5];
    const float* bn1m = (const float*)d_in[6];
    const float* bn1v = (const float*)d_in[7];
    const float* bn2g = (const float*)d_in[8];
    const float* bn2b = (const float*)d_in[9];
    const float* bn2m = (const float*)d_in[10];
    const float* bn2v = (const float*)d_in[11];
    const float* bscg = (const float*)d_in[12];
    const float* bscb = (const float*)d_in[13];
    const float* bscm = (const float*)d_in[14];
    const float* bscv = (const float*)d_in[15];

    const size_t NB = (size_t)32 * 256 * 28 * 28;          // 6,422,528
    float* ws = (float*)d_ws;
    size_t off = 0;
    float* W1n  = ws + off; off += 256 * 128 * 9;
    float* W2n  = ws + off; off += 256 * 256 * 9;
    float* bn1s = ws + off; off += 256;  float* bn1t = ws + off; off += 256;
    float* bn2s = ws + off; off += 256;  float* bn2t = ws + off; off += 256;
    float* bscs = ws + off; off += 256;  float* bsct = ws + off; off += 256;
    float* B1   = ws + off; off += NB;
    float* B2   = ws + off; off += NB;
    float* B3   = ws + off; off += NB;
    float* BR   = ws + off; off += 2 * NB;   // 32*128*56*56 = 2*NB exactly
    float* BRa = BR, * BRb = BR + NB;
    if (off * sizeof(float) > ws_size) return;  // workspace too small: bail loudly

    float* outp = (float*)d_out;

    // FISTA momentum coefficients (t-sequence is data-independent)
    double t = 1.0; float al[3];
    for (int i = 0; i < 3; ++i) {
        double tn = (1.0 + sqrt(1.0 + 4.0 * t * t)) / 2.0;
        al[i] = (float)((t - 1.0) / tn); t = tn;
    }
    // al[0] = 0 exactly -> iteration 1 uses a == c directly (no comb pass)

    const dim3 blk(256);
    const dim3 gF(13, 4, 32);   // 784 px -> 13 tiles, 256 co -> 4 tiles
    const dim3 gT2(52, 2, 32);  // 4 parity quadrants * 13 tiles, 128 co -> 2
    const int n4 = (int)(NB / 4);
    const dim3 gC((n4 + 255) / 256);
    const float* NUL = nullptr;

    // ---- weight / BN prep ----
    norm_w_kernel<<<256, blk, 0, stream>>>(W1, W1n, 128 * 9);
    norm_w_kernel<<<256, blk, 0, stream>>>(W2, W2n, 256 * 9);
    bn_prep_kernel<<<1, blk, 0, stream>>>(bn1g, bn1b, bn1m, bn1v, bn1s, bn1t, 256);
    bn_prep_kernel<<<1, blk, 0, stream>>>(bn2g, bn2b, bn2m, bn2v, bn2s, bn2t, 256);
    bn_prep_kernel<<<1, blk, 0, stream>>>(bscg, bscb, bscm, bscv, bscs, bsct, 256);

    // ================= Stage A: dict_conv(x, W1, stride 2) =================
    // c0 = relu(MU*conv(x) - 0.01)            -> B1
    conv_gemm<3,2,1,0><<<gF, blk, 0, stream>>>(x, W1n, B1,
        128, 256, 56, 56, 28, 28, 128*9, 9, 13,
        MU_F, NUL, 0.f, -SHRINK_F, 1, NUL, NUL, NUL, 0);

    // iter 1 (alpha=0 -> a = c0 = B1)
    conv_gemm<3,2,1,2><<<gT2, blk, 0, stream>>>(B1, W1n, BR,        // r = x - convT(a)
        256, 128, 28, 28, 56, 56, 9, 128*9, 13,
        -1.f, x, 1.f, 0.f, 0, NUL, NUL, NUL, 0);
    conv_gemm<3,2,1,0><<<gF, blk, 0, stream>>>(BR, W1n, B3,         // c1 = relu(a + MU*conv(r) - .01)
        128, 256, 56, 56, 28, 28, 128*9, 9, 13,
        MU_F, B1, 1.f, -SHRINK_F, 1, NUL, NUL, NUL, 0);
    // pre=B1, c=B3

    // iter 2
    comb_kernel<<<gC, blk, 0, stream>>>(B3, B1, B2, 1.f + al[1], -al[1], n4); // a -> B2
    conv_gemm<3,2,1,2><<<gT2, blk, 0, stream>>>(B2, W1n, BR,
        256, 128, 28, 28, 56, 56, 9, 128*9, 13,
        -1.f, x, 1.f, 0.f, 0, NUL, NUL, NUL, 0);
    conv_gemm<3,2,1,0><<<gF, blk, 0, stream>>>(BR, W1n, B1,
        128, 256, 56, 56, 28, 28, 128*9, 9, 13,
        MU_F, B2, 1.f, -SHRINK_F, 1, NUL, NUL, NUL, 0);
    // pre=B3, c=B1

    // iter 3 (+ fused BN1) -> y1 in B3
    comb_kernel<<<gC, blk, 0, stream>>>(B1, B3, B2, 1.f + al[2], -al[2], n4); // a -> B2
    conv_gemm<3,2,1,2><<<gT2, blk, 0, stream>>>(B2, W1n, BR,
        256, 128, 28, 28, 56, 56, 9, 128*9, 13,
        -1.f, x, 1.f, 0.f, 0, NUL, NUL, NUL, 0);
    conv_gemm<3,2,1,0><<<gF, blk, 0, stream>>>(BR, W1n, B3,         // y1 = bn1(relu(...))
        128, 256, 56, 56, 28, 28, 128*9, 9, 13,
        MU_F, B2, 1.f, -SHRINK_F, 1, bn1s, bn1t, NUL, 0);

    // ================= Stage B: dict_conv(y1, W2, stride 1) ================
    // c0 = relu(MU*conv(y1) - .01) -> B1
    conv_gemm<3,1,1,0><<<gF, blk, 0, stream>>>(B3, W2n, B1,
        256, 256, 28, 28, 28, 28, 256*9, 9, 13,
        MU_F, NUL, 0.f, -SHRINK_F, 1, NUL, NUL, NUL, 0);

    // iter 1 (a = c0 = B1)
    conv_gemm<3,1,1,1><<<gF, blk, 0, stream>>>(B1, W2n, BRa,        // r = y1 - convT(a)
        256, 256, 28, 28, 28, 28, 9, 256*9, 13,
        -1.f, B3, 1.f, 0.f, 0, NUL, NUL, NUL, 0);
    conv_gemm<3,1,1,0><<<gF, blk, 0, stream>>>(BRa, W2n, B2,
        256, 256, 28, 28, 28, 28, 256*9, 9, 13,
        MU_F, B1, 1.f, -SHRINK_F, 1, NUL, NUL, NUL, 0);
    // pre=B1, c=B2

    // iter 2
    comb_kernel<<<gC, blk, 0, stream>>>(B2, B1, BRb, 1.f + al[1], -al[1], n4); // a -> BRb
    conv_gemm<3,1,1,1><<<gF, blk, 0, stream>>>(BRb, W2n, BRa,
        256, 256, 28, 28, 28, 28, 9, 256*9, 13,
        -1.f, B3, 1.f, 0.f, 0, NUL, NUL, NUL, 0);
    conv_gemm<3,1,1,0><<<gF, blk, 0, stream>>>(BRa, W2n, B1,
        256, 256, 28, 28, 28, 28, 256*9, 9, 13,
        MU_F, BRb, 1.f, -SHRINK_F, 1, NUL, NUL, NUL, 0);
    // pre=B2, c=B1

    // iter 3 + shortcut + fused BN2 + final relu -> d_out
    comb_kernel<<<gC, blk, 0, stream>>>(B1, B2, BRb, 1.f + al[2], -al[2], n4); // a -> BRb
    conv_gemm<3,1,1,1><<<gF, blk, 0, stream>>>(BRb, W2n, BRa,
        256, 256, 28, 28, 28, 28, 9, 256*9, 13,
        -1.f, B3, 1.f, 0.f, 0, NUL, NUL, NUL, 0);
    conv_gemm<1,2,0,0><<<gF, blk, 0, stream>>>(x, Wsc, B2,          // sc = bnsc(conv1x1(x))
        128, 256, 56, 56, 28, 28, 128, 1, 13,
        1.f, NUL, 0.f, 0.f, 0, bscs, bsct, NUL, 0);
    conv_gemm<3,1,1,0><<<gF, blk, 0, stream>>>(BRa, W2n, outp,      // relu(bn2(c3) + sc)
        256, 256, 28, 28, 28, 28, 256*9, 9, 13,
        MU_F, BRb, 1.f, -SHRINK_F, 1, bn2s, bn2t, B2, 1);
}

// Round 2
// 1718.292 us; speedup vs baseline: 6.8883x; 6.8883x over previous
//
#include <hip/hip_runtime.h>
#include <math.h>

#define MU_F 0.1f
#define SHRINK_F 0.01f   // LMBD * MU
#define BN_EPS_F 1e-5f

typedef _Float16 half_t;
typedef _Float16 half8 __attribute__((ext_vector_type(8)));
typedef float f32x4 __attribute__((ext_vector_type(4)));

#define LROW 40   // LDS row stride in halves (80B: 16B aligned, 2-way bank alias = free)

// ---------------------------------------------------------------------------
// MFMA implicit-GEMM conv. C[co][px] = sum_k A[co][k] * B[k][px], k=(tap,c).
//   A = packed weights, hi+lo fp16 split (2 MFMAs/tile -> ~2^-11 product err)
//   B = NHWC fp16 activations (hi only)
// MODE 0: forward conv stride S pad PAD; MODE 1: convT stride 1;
// MODE 2: convT stride 2 (pad 1, outpad 1), parity-quadrant px mapping.
// Block: 128co x 64px, 4 waves (each wave 32co x 64px), K-chunk 32.
// Frag layout (16x16x32): A row=l&15, k=(l>>4)*8+j ; B col=l&15, same k;
// C/D col=l&15, row=(l>>4)*4+reg  [m89-verified, dtype-independent].
// ---------------------------------------------------------------------------
template<int KS, int S, int PAD, int MODE>
__global__ __launch_bounds__(256, 4)
void conv_mfma(const half_t* __restrict__ Agh, const half_t* __restrict__ Agl,
               const half_t* __restrict__ Xh,
               float* __restrict__ outF, half_t* __restrict__ outH,
               const half_t* __restrict__ auxH, const float* __restrict__ auxF,
               int CA, int Cout, int Hin, int Win, int Hout, int Wout, int ptiles,
               float alpha, float beta, float delta, int relu1,
               const float* __restrict__ pscale, const float* __restrict__ pbias,
               const float* __restrict__ aux3, int relu2)
{
    __shared__ __align__(16) half_t sm[(128 + 128 + 64) * LROW];
    half_t* LAh = sm;
    half_t* LAl = sm + 128 * LROW;
    half_t* LB  = sm + 256 * LROW;

    const int tid = threadIdx.x;
    const int wv = tid >> 6, ln = tid & 63;
    const int n = blockIdx.z;
    const int co0 = blockIdx.y * 128;

    int eh = 0, ew = 0, p0;
    if (MODE == 2) {
        int q = blockIdx.x / ptiles;
        p0 = (blockIdx.x - q * ptiles) * 64;
        eh = q >> 1; ew = q & 1;
    } else {
        p0 = blockIdx.x * 64;
    }

    const int Wd  = (MODE == 2) ? (Wout >> 1) : Wout;
    const int Hd  = (MODE == 2) ? (Hout >> 1) : Hout;
    const int PHW = Hd * Wd;
    const int K9  = KS * KS * CA;

    // staging roles: thread t -> row t>>2, 16B segment t&3 (for both A and B)
    const int part  = tid & 3;
    const int arow0 = tid >> 2;
    const int prow  = tid >> 2;
    const int bpx   = p0 + prow;
    const bool bok0 = bpx < PHW;
    const int bph   = bok0 ? (bpx / Wd) : 0;
    const int bpw   = bpx - bph * Wd;

    const size_t abase0 = (size_t)(co0 + arow0) * K9 + part * 8;
    const size_t abase1 = abase0 + (size_t)64 * K9;

    f32x4 acc[2][4] = {};

    for (int kh = 0; kh < KS; ++kh)
    for (int kw = 0; kw < KS; ++kw) {
        if (MODE == 2) {
            // tap parity must match pixel parity class (block-uniform skip)
            if ((((kh ^ (eh + 1)) & 1) != 0) || (((kw ^ (ew + 1)) & 1) != 0)) continue;
        }
        const int tap = kh * KS + kw;
        bool bok = bok0;
        int hh, ww2;
        if (MODE == 0) {
            hh = bph * S - PAD + kh; ww2 = bpw * S - PAD + kw;
            bok = bok && (unsigned)hh < (unsigned)Hin && (unsigned)ww2 < (unsigned)Win;
        } else if (MODE == 1) {
            hh = bph + PAD - kh; ww2 = bpw + PAD - kw;
            bok = bok && (unsigned)hh < (unsigned)Hin && (unsigned)ww2 < (unsigned)Win;
        } else {
            int nh = 2 * bph + eh + PAD - kh, nw = 2 * bpw + ew + PAD - kw;
            hh = nh >> 1; ww2 = nw >> 1;
            bok = bok && nh >= 0 && nw >= 0 && hh < Hin && ww2 < Win;
        }
        size_t bbase = 0;
        if (bok) bbase = ((size_t)(n * Hin + hh) * Win + ww2) * CA + part * 8;
        const size_t atap = (size_t)tap * CA;

        for (int c0 = 0; c0 < CA; c0 += 32) {
            half8 a0h = *(const half8*)(Agh + abase0 + atap + c0);
            half8 a0l = *(const half8*)(Agl + abase0 + atap + c0);
            half8 a1h = *(const half8*)(Agh + abase1 + atap + c0);
            half8 a1l = *(const half8*)(Agl + abase1 + atap + c0);
            half8 bv = {};
            if (bok) bv = *(const half8*)(Xh + bbase + c0);
            *(half8*)(LAh +  arow0       * LROW + part * 8) = a0h;
            *(half8*)(LAl +  arow0       * LROW + part * 8) = a0l;
            *(half8*)(LAh + (arow0 + 64) * LROW + part * 8) = a1h;
            *(half8*)(LAl + (arow0 + 64) * LROW + part * 8) = a1l;
            *(half8*)(LB  +  prow        * LROW + part * 8) = bv;
            __syncthreads();

            const int fr = ln & 15;
            const int ko = (ln >> 4) * 8;
            const int ar = (wv * 32 + fr) * LROW + ko;
            half8 fa0h = *(const half8*)(LAh + ar);
            half8 fa0l = *(const half8*)(LAl + ar);
            half8 fa1h = *(const half8*)(LAh + ar + 16 * LROW);
            half8 fa1l = *(const half8*)(LAl + ar + 16 * LROW);
#pragma unroll
            for (int t = 0; t < 4; ++t) {
                half8 fb = *(const half8*)(LB + (t * 16 + fr) * LROW + ko);
                acc[0][t] = __builtin_amdgcn_mfma_f32_16x16x32_f16(fa0h, fb, acc[0][t], 0, 0, 0);
                acc[0][t] = __builtin_amdgcn_mfma_f32_16x16x32_f16(fa0l, fb, acc[0][t], 0, 0, 0);
                acc[1][t] = __builtin_amdgcn_mfma_f32_16x16x32_f16(fa1h, fb, acc[1][t], 0, 0, 0);
                acc[1][t] = __builtin_amdgcn_mfma_f32_16x16x32_f16(fa1l, fb, acc[1][t], 0, 0, 0);
            }
            __syncthreads();
        }
    }

    // epilogue: v = alpha*acc + delta (+beta*aux); relu1; bn-fold; +aux3; relu2
    const int fr = ln & 15;
    const int rg = ln >> 4;
#pragma unroll
    for (int t = 0; t < 4; ++t) {
        int px = p0 + t * 16 + fr;
        if (px >= PHW) continue;
        int ph = px / Wd, pw = px - ph * Wd;
        int oh, ow;
        if (MODE == 2) { oh = 2 * ph + eh; ow = 2 * pw + ew; }
        else           { oh = ph;          ow = pw; }
        size_t ghwc = ((size_t)(n * Hout + oh) * Wout + ow) * Cout;
#pragma unroll
        for (int sub = 0; sub < 2; ++sub) {
#pragma unroll
            for (int r = 0; r < 4; ++r) {
                int co_l = co0 + wv * 32 + sub * 16 + rg * 4 + r;
                size_t fidx = ((size_t)(n * Cout + co_l) * Hout + oh) * Wout + ow;
                float v = alpha * acc[sub][t][r] + delta;
                if (auxH) v += beta * (float)auxH[ghwc + co_l];
                if (auxF) v += beta * auxF[fidx];
                if (relu1) v = fmaxf(v, 0.f);
                if (pscale) v = pscale[co_l] * v + pbias[co_l];
                if (aux3) v += aux3[fidx];
                if (relu2) v = fmaxf(v, 0.f);
                if (outH) outH[ghwc + co_l] = (half_t)v;
                else      outF[fidx] = v;
            }
        }
    }
}

// normalize (optional) + pack weights to fp16 hi/lo, [co][tap][ci] and [ci][tap][co]
template<int KT>
__global__ __launch_bounds__(256)
void pack_w(const float* __restrict__ W, half_t* __restrict__ Wh, half_t* __restrict__ Wl,
            half_t* __restrict__ WTh, half_t* __restrict__ WTl,
            int Cin, int Cout, int do_norm)
{
    __shared__ float red[256];
    int co = blockIdx.x, tid = threadIdx.x;
    int CK = Cin * KT;
    const float* w = W + (size_t)co * CK;
    float inv = 1.f;
    if (do_norm) {
        float s = 0.f;
        for (int i = tid; i < CK; i += 256) { float v = w[i]; s += v * v; }
        red[tid] = s; __syncthreads();
        for (int o = 128; o > 0; o >>= 1) {
            if (tid < o) red[tid] += red[tid + o];
            __syncthreads();
        }
        inv = 1.f / (sqrtf(red[0]) + 1e-12f);
    }
    for (int i = tid; i < CK; i += 256) {
        int ci = i / KT, tap = i - ci * KT;
        float v = w[i] * inv;
        half_t h = (half_t)v;
        half_t l = (half_t)(v - (float)h);
        size_t oi = ((size_t)co * KT + tap) * Cin + ci;
        Wh[oi] = h; Wl[oi] = l;
        if (WTh) {
            size_t ti = ((size_t)ci * KT + tap) * Cout + co;
            WTh[ti] = h; WTl[ti] = l;
        }
    }
}

// x (32,128,56,56) NCHW fp32 -> NHWC fp16 (hi only)
__global__ __launch_bounds__(256)
void tx_kernel(const float* __restrict__ x, half_t* __restrict__ xTh)
{
    __shared__ __align__(16) half_t tl[56 * 136];
    int h = blockIdx.x, n = blockIdx.y, tid = threadIdx.x;
    for (int it = 0; it < 28; ++it) {
        int id = tid + it * 256;                 // 128*56 = 7168 total
        int c = id / 56, w0 = id - c * 56;
        tl[w0 * 136 + c] = (half_t)x[(((size_t)n * 128 + c) * 56 + h) * 56 + w0];
    }
    __syncthreads();
    if (tid < 224) {
        int w0 = tid >> 2, part = tid & 3;
        size_t base = (((size_t)n * 56 + h) * 56 + w0) * 128 + part * 32;
#pragma unroll
        for (int j = 0; j < 4; ++j)
            *(half8*)(xTh + base + j * 8) = *(const half8*)(tl + w0 * 136 + part * 32 + j * 8);
    }
}

// a = w1*c + w2*c_pre  on fp16 planes, 8-wide
__global__ __launch_bounds__(256)
void comb_kernel(const half_t* __restrict__ c, const half_t* __restrict__ p,
                 half_t* __restrict__ a, float w1, float w2, int n8)
{
    int i = blockIdx.x * 256 + threadIdx.x;
    if (i >= n8) return;
    half8 cv = ((const half8*)c)[i];
    half8 pv = ((const half8*)p)[i];
    half8 r;
#pragma unroll
    for (int j = 0; j < 8; ++j) r[j] = (half_t)(w1 * (float)cv[j] + w2 * (float)pv[j]);
    ((half8*)a)[i] = r;
}

__global__ __launch_bounds__(256)
void bn_prep_kernel(const float* __restrict__ g, const float* __restrict__ b,
                    const float* __restrict__ m, const float* __restrict__ v,
                    float* __restrict__ s, float* __restrict__ t, int C)
{
    int i = blockIdx.x * 256 + threadIdx.x;
    if (i < C) {
        float sc = g[i] * rsqrtf(v[i] + BN_EPS_F);
        s[i] = sc; t[i] = b[i] - m[i] * sc;
    }
}

extern "C" void kernel_launch(void* const* d_in, const int* in_sizes, int n_in,
                              void* d_out, int out_size, void* d_ws, size_t ws_size,
                              hipStream_t stream)
{
    (void)in_sizes; (void)n_in; (void)out_size;
    const float* x    = (const float*)d_in[0];
    const float* W1   = (const float*)d_in[1];
    const float* W2   = (const float*)d_in[2];
    const float* Wsc  = (const float*)d_in[3];
    const float* bn1g = (const float*)d_in[4];
    const float* bn1b = (const float*)d_in[5];
    const float* bn1m = (const float*)d_in[6];
    const float* bn1v = (const float*)d_in[7];
    const float* bn2g = (const float*)d_in[8];
    const float* bn2b = (const float*)d_in[9];
    const float* bn2m = (const float*)d_in[10];
    const float* bn2v = (const float*)d_in[11];
    const float* bscg = (const float*)d_in[12];
    const float* bscb = (const float*)d_in[13];
    const float* bscm = (const float*)d_in[14];
    const float* bscv = (const float*)d_in[15];

    const size_t NB   = (size_t)32 * 256 * 28 * 28;   // 6,422,528
    const size_t NX   = (size_t)32 * 128 * 56 * 56;   // 12,845,056

    char* base = (char*)d_ws;
    size_t off = 0;
    auto alloc = [&](size_t nbytes) -> void* {
        void* r = base + off;
        off = (off + nbytes + 255) & ~(size_t)255;
        return r;
    };
    half_t* Wh1  = (half_t*)alloc(294912 * 2);
    half_t* Wl1  = (half_t*)alloc(294912 * 2);
    half_t* WTh1 = (half_t*)alloc(294912 * 2);
    half_t* WTl1 = (half_t*)alloc(294912 * 2);
    half_t* Wh2  = (half_t*)alloc(589824 * 2);
    half_t* Wl2  = (half_t*)alloc(589824 * 2);
    half_t* WTh2 = (half_t*)alloc(589824 * 2);
    half_t* WTl2 = (half_t*)alloc(589824 * 2);
    half_t* Wsch = (half_t*)alloc(32768 * 2);
    half_t* Wscl = (half_t*)alloc(32768 * 2);
    float* bn1s = (float*)alloc(256 * 4);  float* bn1t = (float*)alloc(256 * 4);
    float* bn2s = (float*)alloc(256 * 4);  float* bn2t = (float*)alloc(256 * 4);
    float* bscs = (float*)alloc(256 * 4);  float* bsct = (float*)alloc(256 * 4);
    half_t* xTh  = (half_t*)alloc(NX * 2);   // aliased as r56h after shortcut conv
    half_t* r56h = xTh;                      // xTh dead after launches 8-9 (fixed order)
    half_t* Pa   = (half_t*)alloc(NB * 2);
    half_t* Pb   = (half_t*)alloc(NB * 2);
    half_t* Pc   = (half_t*)alloc(NB * 2);
    half_t* Py   = (half_t*)alloc(NB * 2);
    half_t* r28h = (half_t*)alloc(NB * 2);
    float*  scF  = (float*)alloc(NB * 4);
    if (off > ws_size) return;   // workspace too small -> fail loudly

    float* outp = (float*)d_out;

    // FISTA momentum coefficients (data-independent)
    double t = 1.0; float al[3];
    for (int i = 0; i < 3; ++i) {
        double tn = (1.0 + sqrt(1.0 + 4.0 * t * t)) / 2.0;
        al[i] = (float)((t - 1.0) / tn); t = tn;
    }
    // al[0] == 0 -> iteration 1 uses a == c directly

    const dim3 blk(256);
    const dim3 gF(13, 2, 32);    // 784 px -> 13 tiles, 256 co -> 2 x 128
    const dim3 gT2(52, 1, 32);   // 4 parity quadrants x 13, 128 co -> 1
    const int n8 = (int)(NB / 8);
    const dim3 gC((n8 + 255) / 256);
    const float* NF = nullptr;
    const half_t* NH = nullptr;
    float* NFo = nullptr;
    half_t* NHo = nullptr;

    // ---- prep ----
    pack_w<9><<<256, blk, 0, stream>>>(W1, Wh1, Wl1, WTh1, WTl1, 128, 256, 1);
    pack_w<9><<<256, blk, 0, stream>>>(W2, Wh2, Wl2, WTh2, WTl2, 256, 256, 1);
    pack_w<1><<<256, blk, 0, stream>>>(Wsc, Wsch, Wscl, nullptr, nullptr, 128, 256, 0);
    bn_prep_kernel<<<1, blk, 0, stream>>>(bn1g, bn1b, bn1m, bn1v, bn1s, bn1t, 256);
    bn_prep_kernel<<<1, blk, 0, stream>>>(bn2g, bn2b, bn2m, bn2v, bn2s, bn2t, 256);
    bn_prep_kernel<<<1, blk, 0, stream>>>(bscg, bscb, bscm, bscv, bscs, bsct, 256);
    tx_kernel<<<dim3(56, 32), blk, 0, stream>>>(x, xTh);

    // ================= Stage A: dict_conv(x, W1, stride 2) =================
    // c0 = relu(MU*conv(x) - shr) -> Pa
    conv_mfma<3,2,1,0><<<gF, blk, 0, stream>>>(Wh1, Wl1, xTh, NFo, Pa, NH, NF,
        128, 256, 56, 56, 28, 28, 13, MU_F, 0.f, -SHRINK_F, 1, NF, NF, NF, 0);
    // shortcut (must precede r56h aliasing of xTh): sc = bnsc(conv1x1(x))
    conv_mfma<1,2,0,0><<<gF, blk, 0, stream>>>(Wsch, Wscl, xTh, scF, NHo, NH, NF,
        128, 256, 56, 56, 28, 28, 13, 1.f, 0.f, 0.f, 0, bscs, bsct, NF, 0);

    // iter 1 (a = c0 = Pa)
    conv_mfma<3,2,1,2><<<gT2, blk, 0, stream>>>(WTh1, WTl1, Pa, NFo, r56h, NH, x,
        256, 128, 28, 28, 56, 56, 13, -1.f, 1.f, 0.f, 0, NF, NF, NF, 0);
    conv_mfma<3,2,1,0><<<gF, blk, 0, stream>>>(Wh1, Wl1, r56h, NFo, Pb, Pa, NF,
        128, 256, 56, 56, 28, 28, 13, MU_F, 1.f, -SHRINK_F, 1, NF, NF, NF, 0);
    // pre=Pa, c=Pb

    // iter 2
    comb_kernel<<<gC, blk, 0, stream>>>(Pb, Pa, Pc, 1.f + al[1], -al[1], n8);
    conv_mfma<3,2,1,2><<<gT2, blk, 0, stream>>>(WTh1, WTl1, Pc, NFo, r56h, NH, x,
        256, 128, 28, 28, 56, 56, 13, -1.f, 1.f, 0.f, 0, NF, NF, NF, 0);
    conv_mfma<3,2,1,0><<<gF, blk, 0, stream>>>(Wh1, Wl1, r56h, NFo, Pa, Pc, NF,
        128, 256, 56, 56, 28, 28, 13, MU_F, 1.f, -SHRINK_F, 1, NF, NF, NF, 0);
    // pre=Pb, c=Pa

    // iter 3 + fused BN1 -> y1 in Py
    comb_kernel<<<gC, blk, 0, stream>>>(Pa, Pb, Pc, 1.f + al[2], -al[2], n8);
    conv_mfma<3,2,1,2><<<gT2, blk, 0, stream>>>(WTh1, WTl1, Pc, NFo, r56h, NH, x,
        256, 128, 28, 28, 56, 56, 13, -1.f, 1.f, 0.f, 0, NF, NF, NF, 0);
    conv_mfma<3,2,1,0><<<gF, blk, 0, stream>>>(Wh1, Wl1, r56h, NFo, Py, Pc, NF,
        128, 256, 56, 56, 28, 28, 13, MU_F, 1.f, -SHRINK_F, 1, bn1s, bn1t, NF, 0);

    // ================= Stage B: dict_conv(y1, W2, stride 1) ================
    conv_mfma<3,1,1,0><<<gF, blk, 0, stream>>>(Wh2, Wl2, Py, NFo, Pa, NH, NF,
        256, 256, 28, 28, 28, 28, 13, MU_F, 0.f, -SHRINK_F, 1, NF, NF, NF, 0);

    // iter 1 (a = c0 = Pa)
    conv_mfma<3,1,1,1><<<gF, blk, 0, stream>>>(WTh2, WTl2, Pa, NFo, r28h, Py, NF,
        256, 256, 28, 28, 28, 28, 13, -1.f, 1.f, 0.f, 0, NF, NF, NF, 0);
    conv_mfma<3,1,1,0><<<gF, blk, 0, stream>>>(Wh2, Wl2, r28h, NFo, Pb, Pa, NF,
        256, 256, 28, 28, 28, 28, 13, MU_F, 1.f, -SHRINK_F, 1, NF, NF, NF, 0);
    // pre=Pa, c=Pb

    // iter 2
    comb_kernel<<<gC, blk, 0, stream>>>(Pb, Pa, Pc, 1.f + al[1], -al[1], n8);
    conv_mfma<3,1,1,1><<<gF, blk, 0, stream>>>(WTh2, WTl2, Pc, NFo, r28h, Py, NF,
        256, 256, 28, 28, 28, 28, 13, -1.f, 1.f, 0.f, 0, NF, NF, NF, 0);
    conv_mfma<3,1,1,0><<<gF, blk, 0, stream>>>(Wh2, Wl2, r28h, NFo, Pa, Pc, NF,
        256, 256, 28, 28, 28, 28, 13, MU_F, 1.f, -SHRINK_F, 1, NF, NF, NF, 0);
    // pre=Pb, c=Pa

    // iter 3 + BN2 + shortcut add + final relu -> d_out
    comb_kernel<<<gC, blk, 0, stream>>>(Pa, Pb, Pc, 1.f + al[2], -al[2], n8);
    conv_mfma<3,1,1,1><<<gF, blk, 0, stream>>>(WTh2, WTl2, Pc, NFo, r28h, Py, NF,
        256, 256, 28, 28, 28, 28, 13, -1.f, 1.f, 0.f, 0, NF, NF, NF, 0);
    conv_mfma<3,1,1,0><<<gF, blk, 0, stream>>>(Wh2, Wl2, r28h, outp, NHo, Pc, NF,
        256, 256, 28, 28, 28, 28, 13, MU_F, 1.f, -SHRINK_F, 1, bn2s, bn2t, scF, 1);
}

// Round 3
// 1329.949 us; speedup vs baseline: 8.8997x; 1.2920x over previous
//
#include <hip/hip_runtime.h>
#include <math.h>

#define MU_F 0.1f
#define SHRINK_F 0.01f   // LMBD * MU
#define BN_EPS_F 1e-5f

typedef _Float16 half_t;
typedef _Float16 half8 __attribute__((ext_vector_type(8)));
typedef float f32x4 __attribute__((ext_vector_type(4)));

#define LROW 40   // LDS row stride in halves (80B: 16B aligned, worst 2-way bank alias = free)

// ---------------------------------------------------------------------------
// MFMA implicit-GEMM conv, m97 geometry: block = 128co x 128px, 4 waves of
// 64co x 64px (2x2), K-chunk 32. Per chunk per wave: 8 ds_read_b128 + 16 MFMA
// -> 32 useful FLOP per LDS byte read (the m97 ratio).
//   A[co][k=(tap,c)] = packed fp16 weights ;  B[k][px] = NHWC fp16 activations
// MODE 0: forward conv stride S pad PAD; MODE 1: convT stride 1 (pad 1);
// MODE 2: convT stride 2 (pad 1, outpad 1) via parity-quadrant px mapping.
// Frag layout (16x16x32): A row=l&15, k=(l>>4)*8+j ; B col=l&15 same k;
// C/D col=l&15, row=(l>>4)*4+reg  [m89-verified, dtype-independent].
// ---------------------------------------------------------------------------
template<int KS, int S, int PAD, int MODE>
__global__ __launch_bounds__(256, 2)
void conv_big(const half_t* __restrict__ Ag, const half_t* __restrict__ Xh,
              float* __restrict__ outF, half_t* __restrict__ outH,
              const half_t* __restrict__ auxH, const float* __restrict__ auxF,
              int CA, int Cout, int Hin, int Win, int Hout, int Wout, int ptiles,
              float alpha, float beta, float delta, int relu1,
              const float* __restrict__ pscale, const float* __restrict__ pbias,
              const float* __restrict__ aux3, int relu2)
{
    __shared__ __align__(16) half_t sm[256 * LROW];
    half_t* LA = sm;                 // 128 rows (co)
    half_t* LB = sm + 128 * LROW;    // 128 rows (px)

    const int tid = threadIdx.x;
    const int wv = tid >> 6, ln = tid & 63;
    const int n = blockIdx.z;
    const int co0 = blockIdx.y * 128;
    const int wco = (wv & 1) * 64, wpx = (wv >> 1) * 64;

    int eh = 0, ew = 0, p0;
    if (MODE == 2) {
        int q = blockIdx.x / ptiles;
        p0 = (blockIdx.x - q * ptiles) * 128;
        eh = q >> 1; ew = q & 1;
    } else {
        p0 = blockIdx.x * 128;
    }

    const int Wd  = (MODE == 2) ? (Wout >> 1) : Wout;
    const int Hd  = (MODE == 2) ? (Hout >> 1) : Hout;
    const int PHW = Hd * Wd;
    const int K9  = KS * KS * CA;

    const int part = tid & 3;
    const int row0 = tid >> 2;

    size_t abase[2];
    abase[0] = (size_t)(co0 + row0) * K9 + part * 8;
    abase[1] = abase[0] + (size_t)64 * K9;

    int bph[2], bpw[2];
    bool bok0[2];
#pragma unroll
    for (int i = 0; i < 2; ++i) {
        int px = p0 + row0 + i * 64;
        bok0[i] = px < PHW;
        int ph = bok0[i] ? (px / Wd) : 0;
        bph[i] = ph; bpw[i] = px - ph * Wd;
    }

    f32x4 acc[4][4] = {};

    for (int kh = 0; kh < KS; ++kh)
    for (int kw = 0; kw < KS; ++kw) {
        if (MODE == 2) {
            if ((((kh ^ (eh + 1)) & 1) != 0) || (((kw ^ (ew + 1)) & 1) != 0)) continue;
        }
        const int tap = kh * KS + kw;
        size_t bb[2]; bool bvld[2];
#pragma unroll
        for (int i = 0; i < 2; ++i) {
            bool ok = bok0[i];
            int hh, ww2;
            if (MODE == 0) {
                hh = bph[i] * S - PAD + kh; ww2 = bpw[i] * S - PAD + kw;
                ok = ok && (unsigned)hh < (unsigned)Hin && (unsigned)ww2 < (unsigned)Win;
            } else if (MODE == 1) {
                hh = bph[i] + PAD - kh; ww2 = bpw[i] + PAD - kw;
                ok = ok && (unsigned)hh < (unsigned)Hin && (unsigned)ww2 < (unsigned)Win;
            } else {
                int nh = 2 * bph[i] + eh + PAD - kh, nw = 2 * bpw[i] + ew + PAD - kw;
                hh = nh >> 1; ww2 = nw >> 1;
                ok = ok && nh >= 0 && nw >= 0 && hh < Hin && ww2 < Win;
            }
            bvld[i] = ok;
            bb[i] = ok ? (((size_t)(n * Hin + hh) * Win + ww2) * CA + part * 8) : 0;
        }
        const size_t atap = (size_t)tap * CA;

        for (int c0 = 0; c0 < CA; c0 += 32) {
            half8 a0 = *(const half8*)(Ag + abase[0] + atap + c0);
            half8 a1 = *(const half8*)(Ag + abase[1] + atap + c0);
            half8 b0 = {}, b1 = {};
            if (bvld[0]) b0 = *(const half8*)(Xh + bb[0] + c0);
            if (bvld[1]) b1 = *(const half8*)(Xh + bb[1] + c0);
            *(half8*)(LA +  row0       * LROW + part * 8) = a0;
            *(half8*)(LA + (row0 + 64) * LROW + part * 8) = a1;
            *(half8*)(LB +  row0       * LROW + part * 8) = b0;
            *(half8*)(LB + (row0 + 64) * LROW + part * 8) = b1;
            __syncthreads();

            const int fr = ln & 15;
            const int koh = (ln >> 4) * 8;
            half8 fa[4], fb[4];
#pragma unroll
            for (int m = 0; m < 4; ++m)
                fa[m] = *(const half8*)(LA + (wco + m * 16 + fr) * LROW + koh);
#pragma unroll
            for (int t = 0; t < 4; ++t)
                fb[t] = *(const half8*)(LB + (wpx + t * 16 + fr) * LROW + koh);
#pragma unroll
            for (int m = 0; m < 4; ++m)
#pragma unroll
                for (int t = 0; t < 4; ++t)
                    acc[m][t] = __builtin_amdgcn_mfma_f32_16x16x32_f16(fa[m], fb[t], acc[m][t], 0, 0, 0);
            __syncthreads();
        }
    }

    const int fr = ln & 15;
    const int rg = ln >> 4;
#pragma unroll
    for (int t = 0; t < 4; ++t) {
        int px = p0 + wpx + t * 16 + fr;
        if (px >= PHW) continue;
        int ph = px / Wd, pw = px - ph * Wd;
        int oh, ow;
        if (MODE == 2) { oh = 2 * ph + eh; ow = 2 * pw + ew; }
        else           { oh = ph;          ow = pw; }
        size_t ghwc = ((size_t)(n * Hout + oh) * Wout + ow) * Cout;
#pragma unroll
        for (int m = 0; m < 4; ++m) {
#pragma unroll
            for (int r = 0; r < 4; ++r) {
                int co_l = co0 + wco + m * 16 + rg * 4 + r;
                size_t fidx = ((size_t)(n * Cout + co_l) * Hout + oh) * Wout + ow;
                float v = alpha * acc[m][t][r] + delta;
                if (auxH) v += beta * (float)auxH[ghwc + co_l];
                if (auxF) v += beta * auxF[fidx];
                if (relu1) v = fmaxf(v, 0.f);
                if (pscale) v = pscale[co_l] * v + pbias[co_l];
                if (aux3) v += aux3[fidx];
                if (relu2) v = fmaxf(v, 0.f);
                if (outH) outH[ghwc + co_l] = (half_t)v;
                else      outF[fidx] = v;
            }
        }
    }
}

template<int KT>
__global__ __launch_bounds__(256)
void pack_w(const float* __restrict__ W, half_t* __restrict__ Wh,
            half_t* __restrict__ WTh, int Cin, int Cout, int do_norm)
{
    __shared__ float red[256];
    int co = blockIdx.x, tid = threadIdx.x;
    int CK = Cin * KT;
    const float* w = W + (size_t)co * CK;
    float inv = 1.f;
    if (do_norm) {
        float s = 0.f;
        for (int i = tid; i < CK; i += 256) { float v = w[i]; s += v * v; }
        red[tid] = s; __syncthreads();
        for (int o = 128; o > 0; o >>= 1) {
            if (tid < o) red[tid] += red[tid + o];
            __syncthreads();
        }
        inv = 1.f / (sqrtf(red[0]) + 1e-12f);
    }
    for (int i = tid; i < CK; i += 256) {
        int ci = i / KT, tap = i - ci * KT;
        half_t h = (half_t)(w[i] * inv);
        Wh[((size_t)co * KT + tap) * Cin + ci] = h;
        if (WTh) WTh[((size_t)ci * KT + tap) * Cout + co] = h;
    }
}

__global__ __launch_bounds__(256)
void tx_kernel(const float* __restrict__ x, half_t* __restrict__ xTh)
{
    __shared__ __align__(16) half_t tl[56 * 136];
    int h = blockIdx.x, n = blockIdx.y, tid = threadIdx.x;
    for (int it = 0; it < 28; ++it) {
        int id = tid + it * 256;
        int c = id / 56, w0 = id - c * 56;
        tl[w0 * 136 + c] = (half_t)x[(((size_t)n * 128 + c) * 56 + h) * 56 + w0];
    }
    __syncthreads();
    if (tid < 224) {
        int w0 = tid >> 2, part = tid & 3;
        size_t base = (((size_t)n * 56 + h) * 56 + w0) * 128 + part * 32;
#pragma unroll
        for (int j = 0; j < 4; ++j)
            *(half8*)(xTh + base + j * 8) = *(const half8*)(tl + w0 * 136 + part * 32 + j * 8);
    }
}

__global__ __launch_bounds__(256)
void comb_kernel(const half_t* __restrict__ c, const half_t* __restrict__ p,
                 half_t* __restrict__ a, float w1, float w2, int n8)
{
    int i = blockIdx.x * 256 + threadIdx.x;
    if (i >= n8) return;
    half8 cv = ((const half8*)c)[i];
    half8 pv = ((const half8*)p)[i];
    half8 r;
#pragma unroll
    for (int j = 0; j < 8; ++j) r[j] = (half_t)(w1 * (float)cv[j] + w2 * (float)pv[j]);
    ((half8*)a)[i] = r;
}

__global__ __launch_bounds__(256)
void bn_prep_kernel(const float* __restrict__ g, const float* __restrict__ b,
                    const float* __restrict__ m, const float* __restrict__ v,
                    float* __restrict__ s, float* __restrict__ t, int C)
{
    int i = blockIdx.x * 256 + threadIdx.x;
    if (i < C) {
        float sc = g[i] * rsqrtf(v[i] + BN_EPS_F);
        s[i] = sc; t[i] = b[i] - m[i] * sc;
    }
}

extern "C" void kernel_launch(void* const* d_in, const int* in_sizes, int n_in,
                              void* d_out, int out_size, void* d_ws, size_t ws_size,
                              hipStream_t stream)
{
    (void)in_sizes; (void)n_in; (void)out_size;
    const float* x    = (const float*)d_in[0];
    const float* W1   = (const float*)d_in[1];
    const float* W2   = (const float*)d_in[2];
    const float* Wsc  = (const float*)d_in[3];
    const float* bn1g = (const float*)d_in[4];
    const float* bn1b = (const float*)d_in[5];
    const float* bn1m = (const float*)d_in[6];
    const float* bn1v = (const float*)d_in[7];
    const float* bn2g = (const float*)d_in[8];
    const float* bn2b = (const float*)d_in[9];
    const float* bn2m = (const float*)d_in[10];
    const float* bn2v = (const float*)d_in[11];
    const float* bscg = (const float*)d_in[12];
    const float* bscb = (const float*)d_in[13];
    const float* bscm = (const float*)d_in[14];
    const float* bscv = (const float*)d_in[15];

    const size_t NB = (size_t)32 * 256 * 28 * 28;
    const size_t NX = (size_t)32 * 128 * 56 * 56;

    char* base = (char*)d_ws;
    size_t off = 0;
    auto alloc = [&](size_t nbytes) -> void* {
        void* r = base + off;
        off = (off + nbytes + 255) & ~(size_t)255;
        return r;
    };
    half_t* Wh1  = (half_t*)alloc(294912 * 2);
    half_t* WTh1 = (half_t*)alloc(294912 * 2);
    half_t* Wh2  = (half_t*)alloc(589824 * 2);
    half_t* WTh2 = (half_t*)alloc(589824 * 2);
    half_t* Wsch = (half_t*)alloc(32768 * 2);
    float* bn1s = (float*)alloc(256 * 4);  float* bn1t = (float*)alloc(256 * 4);
    float* bn2s = (float*)alloc(256 * 4);  float* bn2t = (float*)alloc(256 * 4);
    float* bscs = (float*)alloc(256 * 4);  float* bsct = (float*)alloc(256 * 4);
    half_t* xTh  = (half_t*)alloc(NX * 2);   // aliased as r56h after shortcut+c0 consume it
    half_t* r56h = xTh;
    half_t* Pa   = (half_t*)alloc(NB * 2);
    half_t* Pb   = (half_t*)alloc(NB * 2);
    half_t* Pc   = (half_t*)alloc(NB * 2);
    half_t* Py   = (half_t*)alloc(NB * 2);
    half_t* r28h = (half_t*)alloc(NB * 2);
    float*  scF  = (float*)alloc(NB * 4);
    if (off > ws_size) return;

    float* outp = (float*)d_out;

    double t = 1.0; float al[3];
    for (int i = 0; i < 3; ++i) {
        double tn = (1.0 + sqrt(1.0 + 4.0 * t * t)) / 2.0;
        al[i] = (float)((t - 1.0) / tn); t = tn;
    }

    const dim3 blk(256);
    const dim3 gF(7, 2, 32);
    const dim3 gT2(28, 1, 32);
    const int n8 = (int)(NB / 8);
    const dim3 gC((n8 + 255) / 256);
    const float* NF = nullptr;
    const half_t* NH = nullptr;
    float* NFo = nullptr;
    half_t* NHo = nullptr;

    pack_w<9><<<256, blk, 0, stream>>>(W1, Wh1, WTh1, 128, 256, 1);
    pack_w<9><<<256, blk, 0, stream>>>(W2, Wh2, WTh2, 256, 256, 1);
    pack_w<1><<<256, blk, 0, stream>>>(Wsc, Wsch, nullptr, 128, 256, 0);
    bn_prep_kernel<<<1, blk, 0, stream>>>(bn1g, bn1b, bn1m, bn1v, bn1s, bn1t, 256);
    bn_prep_kernel<<<1, blk, 0, stream>>>(bn2g, bn2b, bn2m, bn2v, bn2s, bn2t, 256);
    bn_prep_kernel<<<1, blk, 0, stream>>>(bscg, bscb, bscm, bscv, bscs, bsct, 256);
    tx_kernel<<<dim3(56, 32), blk, 0, stream>>>(x, xTh);

    // ================= Stage A =================
    conv_big<3,2,1,0><<<gF, blk, 0, stream>>>(Wh1, xTh, NFo, Pa, NH, NF,
        128, 256, 56, 56, 28, 28, 7, MU_F, 0.f, -SHRINK_F, 1, NF, NF, NF, 0);
    conv_big<1,2,0,0><<<gF, blk, 0, stream>>>(Wsch, xTh, scF, NHo, NH, NF,
        128, 256, 56, 56, 28, 28, 7, 1.f, 0.f, 0.f, 0, bscs, bsct, NF, 0);

    conv_big<3,2,1,2><<<gT2, blk, 0, stream>>>(WTh1, Pa, NFo, r56h, NH, x,
        256, 128, 28, 28, 56, 56, 7, -1.f, 1.f, 0.f, 0, NF, NF, NF, 0);
    conv_big<3,2,1,0><<<gF, blk, 0, stream>>>(Wh1, r56h, NFo, Pb, Pa, NF,
        128, 256, 56, 56, 28, 28, 7, MU_F, 1.f, -SHRINK_F, 1, NF, NF, NF, 0);

    comb_kernel<<<gC, blk, 0, stream>>>(Pb, Pa, Pc, 1.f + al[1], -al[1], n8);
    conv_big<3,2,1,2><<<gT2, blk, 0, stream>>>(WTh1, Pc, NFo, r56h, NH, x,
        256, 128, 28, 28, 56, 56, 7, -1.f, 1.f, 0.f, 0, NF, NF, NF, 0);
    conv_big<3,2,1,0><<<gF, blk, 0, stream>>>(Wh1, r56h, NFo, Pa, Pc, NF,
        128, 256, 56, 56, 28, 28, 7, MU_F, 1.f, -SHRINK_F, 1, NF, NF, NF, 0);

    comb_kernel<<<gC, blk, 0, stream>>>(Pa, Pb, Pc, 1.f + al[2], -al[2], n8);
    conv_big<3,2,1,2><<<gT2, blk, 0, stream>>>(WTh1, Pc, NFo, r56h, NH, x,
        256, 128, 28, 28, 56, 56, 7, -1.f, 1.f, 0.f, 0, NF, NF, NF, 0);
    conv_big<3,2,1,0><<<gF, blk, 0, stream>>>(Wh1, r56h, NFo, Py, Pc, NF,
        128, 256, 56, 56, 28, 28, 7, MU_F, 1.f, -SHRINK_F, 1, bn1s, bn1t, NF, 0);

    // ================= Stage B =================
    conv_big<3,1,1,0><<<gF, blk, 0, stream>>>(Wh2, Py, NFo, Pa, NH, NF,
        256, 256, 28, 28, 28, 28, 7, MU_F, 0.f, -SHRINK_F, 1, NF, NF, NF, 0);

    conv_big<3,1,1,1><<<gF, blk, 0, stream>>>(WTh2, Pa, NFo, r28h, Py, NF,
        256, 256, 28, 28, 28, 28, 7, -1.f, 1.f, 0.f, 0, NF, NF, NF, 0);
    conv_big<3,1,1,0><<<gF, blk, 0, stream>>>(Wh2, r28h, NFo, Pb, Pa, NF,
        256, 256, 28, 28, 28, 28, 7, MU_F, 1.f, -SHRINK_F, 1, NF, NF, NF, 0);

    comb_kernel<<<gC, blk, 0, stream>>>(Pb, Pa, Pc, 1.f + al[1], -al[1], n8);
    conv_big<3,1,1,1><<<gF, blk, 0, stream>>>(WTh2, Pc, NFo, r28h, Py, NF,
        256, 256, 28, 28, 28, 28, 7, -1.f, 1.f, 0.f, 0, NF, NF, NF, 0);
    conv_big<3,1,1,0><<<gF, blk, 0, stream>>>(Wh2, r28h, NFo, Pa, Pc, NF,
        256, 256, 28, 28, 28, 28, 7, MU_F, 1.f, -SHRINK_F, 1, NF, NF, NF, 0);

    comb_kernel<<<gC, blk, 0, stream>>>(Pa, Pb, Pc, 1.f + al[2], -al[2], n8);
    conv_big<3,1,1,1><<<gF, blk, 0, stream>>>(WTh2, Pc, NFo, r28h, Py, NF,
        256, 256, 28, 28, 28, 28, 7, -1.f, 1.f, 0.f, 0, NF, NF, NF, 0);
    conv_big<3,1,1,0><<<gF, blk, 0, stream>>>(Wh2, r28h, outp, NHo, Pc, NF,
        256, 256, 28, 28, 28, 28, 7, MU_F, 1.f, -SHRINK_F, 1, bn2s, bn2t, scF, 1);
}

// Round 4
// 1195.761 us; speedup vs baseline: 9.8984x; 1.1122x over previous
//
#include <hip/hip_runtime.h>
#include <math.h>

#define MU_F 0.1f
#define SHRINK_F 0.01f   // LMBD * MU
#define BN_EPS_F 1e-5f

typedef _Float16 half_t;
typedef _Float16 half8 __attribute__((ext_vector_type(8)));
typedef float f32x4 __attribute__((ext_vector_type(4)));

#define LROW 40   // LDS row stride in halves (80B: 16B aligned; reads 2-way alias = free)

// ---------------------------------------------------------------------------
// MFMA implicit-GEMM conv, software-pipelined:
//   block = 128co x 128px, 4 waves of 64x64, K-chunk 32
//   double-buffered LDS (2 x 20KB) -> ONE barrier per chunk
//   register prefetch: chunk k+2 globals issued during chunk k MFMA section
//   flat chunk loop over (tap, c0) so the pipeline crosses tap boundaries
// A[co][k=(tap,c)] = packed fp16 weights ; B[k][px] = NHWC fp16 activations
// MODE 0: fwd conv stride S pad PAD; MODE 1: convT s1 (pad 1);
// MODE 2: convT s2 (pad 1, outpad 1) via parity-quadrant px mapping; valid
//         taps have closed form kh = ((eh+1)&1) + 2*i (i<1+eh), kw likewise.
// Frag layout (16x16x32): A row=l&15, k=(l>>4)*8+j ; B col=l&15 same k;
// C/D col=l&15, row=(l>>4)*4+reg  [m89-verified, dtype-independent].
// ---------------------------------------------------------------------------
template<int KS, int S, int PAD, int MODE>
__global__ __launch_bounds__(256, 2)
void conv_big(const half_t* __restrict__ Ag, const half_t* __restrict__ Xh,
              float* __restrict__ outF, half_t* __restrict__ outH,
              const half_t* __restrict__ auxH, const float* __restrict__ auxF,
              int CA, int Cout, int Hin, int Win, int Hout, int Wout, int ptiles,
              float alpha, float beta, float delta, int relu1,
              const float* __restrict__ pscale, const float* __restrict__ pbias,
              const float* __restrict__ aux3, int relu2)
{
    __shared__ __align__(16) half_t sm[2 * 256 * LROW];   // 40 KB, ping-pong

    const int tid = threadIdx.x;
    const int wv = tid >> 6, ln = tid & 63;
    const int n = blockIdx.z;
    const int co0 = blockIdx.y * 128;
    const int wco = (wv & 1) * 64, wpx = (wv >> 1) * 64;

    int eh = 0, ew = 0, p0;
    if (MODE == 2) {
        int q = blockIdx.x / ptiles;
        p0 = (blockIdx.x - q * ptiles) * 128;
        eh = q >> 1; ew = q & 1;
    } else {
        p0 = blockIdx.x * 128;
    }

    const int Wd  = (MODE == 2) ? (Wout >> 1) : Wout;
    const int Hd  = (MODE == 2) ? (Hout >> 1) : Hout;
    const int PHW = Hd * Wd;
    const int K9  = KS * KS * CA;

    const int part = tid & 3;
    const int row0 = tid >> 2;

    const size_t abase0 = (size_t)(co0 + row0) * K9 + part * 8;
    const size_t abase1 = abase0 + (size_t)64 * K9;

    int bph[2], bpw[2]; bool bok0[2];
#pragma unroll
    for (int i = 0; i < 2; ++i) {
        int px = p0 + row0 + i * 64;
        bok0[i] = px < PHW;
        int ph = bok0[i] ? (px / Wd) : 0;
        bph[i] = ph; bpw[i] = px - ph * Wd;
    }

    // flat chunk space: flat = ti*cpt + ci ; ti indexes valid taps
    const int cpt = CA >> 5;                 // chunks per tap (4 or 8)
    const int lgc = (cpt == 8) ? 3 : 2;
    int ntap, lgj = 0, phh = 0, pww = 0;
    if (MODE == 2) {
        phh = (eh + 1) & 1; pww = (ew + 1) & 1;
        lgj = ew;                            // log2(valid kw count)
        ntap = (1 + eh) * (1 + ew);
    } else {
        ntap = KS * KS;
    }
    const int total = ntap << lgc;

    // prefetch one chunk's worth of A/B into registers
    auto fetch = [&](int flat, half8& a0, half8& a1, half8& b0, half8& b1) {
        const int ci = flat & (cpt - 1);
        const int ti = flat >> lgc;
        int kh, kw;
        if (MODE == 2) {
            int i2 = ti >> lgj, j = ti & ((1 << lgj) - 1);
            kh = phh + 2 * i2; kw = pww + 2 * j;
        } else if (KS == 3) {
            kh = (ti * 11) >> 5; kw = ti - 3 * kh;   // div-by-3, ti<9
        } else { kh = 0; kw = 0; }
        const int c0 = ci << 5;
        const size_t aoff = (size_t)(kh * KS + kw) * CA + c0;
        a0 = *(const half8*)(Ag + abase0 + aoff);
        a1 = *(const half8*)(Ag + abase1 + aoff);
#pragma unroll
        for (int i = 0; i < 2; ++i) {
            bool ok = bok0[i]; int hh, ww2;
            if (MODE == 0) {
                hh = bph[i] * S - PAD + kh; ww2 = bpw[i] * S - PAD + kw;
                ok = ok && (unsigned)hh < (unsigned)Hin && (unsigned)ww2 < (unsigned)Win;
            } else if (MODE == 1) {
                hh = bph[i] + PAD - kh; ww2 = bpw[i] + PAD - kw;
                ok = ok && (unsigned)hh < (unsigned)Hin && (unsigned)ww2 < (unsigned)Win;
            } else {
                int nh = 2 * bph[i] + eh + PAD - kh, nw = 2 * bpw[i] + ew + PAD - kw;
                hh = nh >> 1; ww2 = nw >> 1;
                ok = ok && nh >= 0 && nw >= 0 && hh < Hin && ww2 < Win;
            }
            half8 v = {};
            if (ok) v = *(const half8*)(Xh + ((size_t)(n * Hin + hh) * Win + ww2) * CA + c0 + part * 8);
            if (i == 0) b0 = v; else b1 = v;
        }
    };

    f32x4 acc[4][4] = {};
    half8 pa0, pa1, pb0, pb1;

    // prologue: chunk 0 -> buf0; issue chunk 1 loads
    fetch(0, pa0, pa1, pb0, pb1);
    {
        half_t* buf = sm;
        *(half8*)(buf +  row0        * LROW + part * 8) = pa0;
        *(half8*)(buf + (row0 +  64) * LROW + part * 8) = pa1;
        *(half8*)(buf + (row0 + 128) * LROW + part * 8) = pb0;
        *(half8*)(buf + (row0 + 192) * LROW + part * 8) = pb1;
    }
    if (total > 1) fetch(1, pa0, pa1, pb0, pb1);
    __syncthreads();

    const int fr = ln & 15, koh = (ln >> 4) * 8;
    for (int k = 0; k < total; ++k) {
        half_t* buf = sm + (k & 1) * (256 * LROW);
        half8 fa[4], fb[4];
#pragma unroll
        for (int m = 0; m < 4; ++m)
            fa[m] = *(const half8*)(buf + (wco + m * 16 + fr) * LROW + koh);
#pragma unroll
        for (int t2 = 0; t2 < 4; ++t2)
            fb[t2] = *(const half8*)(buf + (128 + wpx + t2 * 16 + fr) * LROW + koh);
#pragma unroll
        for (int m = 0; m < 4; ++m)
#pragma unroll
            for (int t2 = 0; t2 < 4; ++t2)
                acc[m][t2] = __builtin_amdgcn_mfma_f32_16x16x32_f16(fa[m], fb[t2], acc[m][t2], 0, 0, 0);
        if (k + 1 < total) {
            half_t* nb = sm + ((k + 1) & 1) * (256 * LROW);
            *(half8*)(nb +  row0        * LROW + part * 8) = pa0;
            *(half8*)(nb + (row0 +  64) * LROW + part * 8) = pa1;
            *(half8*)(nb + (row0 + 128) * LROW + part * 8) = pb0;
            *(half8*)(nb + (row0 + 192) * LROW + part * 8) = pb1;
            if (k + 2 < total) fetch(k + 2, pa0, pa1, pb0, pb1);
            __syncthreads();   // uniform: k+1<total is block-uniform
        }
    }

    // epilogue
    const int rg = ln >> 4;
#pragma unroll
    for (int t = 0; t < 4; ++t) {
        int px = p0 + wpx + t * 16 + fr;
        if (px >= PHW) continue;
        int ph = px / Wd, pw = px - ph * Wd;
        int oh, ow;
        if (MODE == 2) { oh = 2 * ph + eh; ow = 2 * pw + ew; }
        else           { oh = ph;          ow = pw; }
        size_t ghwc = ((size_t)(n * Hout + oh) * Wout + ow) * Cout;
#pragma unroll
        for (int m = 0; m < 4; ++m) {
#pragma unroll
            for (int r = 0; r < 4; ++r) {
                int co_l = co0 + wco + m * 16 + rg * 4 + r;
                size_t fidx = ((size_t)(n * Cout + co_l) * Hout + oh) * Wout + ow;
                float v = alpha * acc[m][t][r] + delta;
                if (auxH) v += beta * (float)auxH[ghwc + co_l];
                if (auxF) v += beta * auxF[fidx];
                if (relu1) v = fmaxf(v, 0.f);
                if (pscale) v = pscale[co_l] * v + pbias[co_l];
                if (aux3) v += aux3[fidx];
                if (relu2) v = fmaxf(v, 0.f);
                if (outH) outH[ghwc + co_l] = (half_t)v;
                else      outF[fidx] = v;
            }
        }
    }
}

template<int KT>
__global__ __launch_bounds__(256)
void pack_w(const float* __restrict__ W, half_t* __restrict__ Wh,
            half_t* __restrict__ WTh, int Cin, int Cout, int do_norm)
{
    __shared__ float red[256];
    int co = blockIdx.x, tid = threadIdx.x;
    int CK = Cin * KT;
    const float* w = W + (size_t)co * CK;
    float inv = 1.f;
    if (do_norm) {
        float s = 0.f;
        for (int i = tid; i < CK; i += 256) { float v = w[i]; s += v * v; }
        red[tid] = s; __syncthreads();
        for (int o = 128; o > 0; o >>= 1) {
            if (tid < o) red[tid] += red[tid + o];
            __syncthreads();
        }
        inv = 1.f / (sqrtf(red[0]) + 1e-12f);
    }
    for (int i = tid; i < CK; i += 256) {
        int ci = i / KT, tap = i - ci * KT;
        half_t h = (half_t)(w[i] * inv);
        Wh[((size_t)co * KT + tap) * Cin + ci] = h;
        if (WTh) WTh[((size_t)ci * KT + tap) * Cout + co] = h;
    }
}

__global__ __launch_bounds__(256)
void tx_kernel(const float* __restrict__ x, half_t* __restrict__ xTh)
{
    __shared__ __align__(16) half_t tl[56 * 136];
    int h = blockIdx.x, n = blockIdx.y, tid = threadIdx.x;
    for (int it = 0; it < 28; ++it) {
        int id = tid + it * 256;
        int c = id / 56, w0 = id - c * 56;
        tl[w0 * 136 + c] = (half_t)x[(((size_t)n * 128 + c) * 56 + h) * 56 + w0];
    }
    __syncthreads();
    if (tid < 224) {
        int w0 = tid >> 2, part = tid & 3;
        size_t base = (((size_t)n * 56 + h) * 56 + w0) * 128 + part * 32;
#pragma unroll
        for (int j = 0; j < 4; ++j)
            *(half8*)(xTh + base + j * 8) = *(const half8*)(tl + w0 * 136 + part * 32 + j * 8);
    }
}

__global__ __launch_bounds__(256)
void comb_kernel(const half_t* __restrict__ c, const half_t* __restrict__ p,
                 half_t* __restrict__ a, float w1, float w2, int n8)
{
    int i = blockIdx.x * 256 + threadIdx.x;
    if (i >= n8) return;
    half8 cv = ((const half8*)c)[i];
    half8 pv = ((const half8*)p)[i];
    half8 r;
#pragma unroll
    for (int j = 0; j < 8; ++j) r[j] = (half_t)(w1 * (float)cv[j] + w2 * (float)pv[j]);
    ((half8*)a)[i] = r;
}

__global__ __launch_bounds__(256)
void bn_prep_kernel(const float* __restrict__ g, const float* __restrict__ b,
                    const float* __restrict__ m, const float* __restrict__ v,
                    float* __restrict__ s, float* __restrict__ t, int C)
{
    int i = blockIdx.x * 256 + threadIdx.x;
    if (i < C) {
        float sc = g[i] * rsqrtf(v[i] + BN_EPS_F);
        s[i] = sc; t[i] = b[i] - m[i] * sc;
    }
}

extern "C" void kernel_launch(void* const* d_in, const int* in_sizes, int n_in,
                              void* d_out, int out_size, void* d_ws, size_t ws_size,
                              hipStream_t stream)
{
    (void)in_sizes; (void)n_in; (void)out_size;
    const float* x    = (const float*)d_in[0];
    const float* W1   = (const float*)d_in[1];
    const float* W2   = (const float*)d_in[2];
    const float* Wsc  = (const float*)d_in[3];
    const float* bn1g = (const float*)d_in[4];
    const float* bn1b = (const float*)d_in[5];
    const float* bn1m = (const float*)d_in[6];
    const float* bn1v = (const float*)d_in[7];
    const float* bn2g = (const float*)d_in[8];
    const float* bn2b = (const float*)d_in[9];
    const float* bn2m = (const float*)d_in[10];
    const float* bn2v = (const float*)d_in[11];
    const float* bscg = (const float*)d_in[12];
    const float* bscb = (const float*)d_in[13];
    const float* bscm = (const float*)d_in[14];
    const float* bscv = (const float*)d_in[15];

    const size_t NB = (size_t)32 * 256 * 28 * 28;
    const size_t NX = (size_t)32 * 128 * 56 * 56;

    char* base = (char*)d_ws;
    size_t off = 0;
    auto alloc = [&](size_t nbytes) -> void* {
        void* r = base + off;
        off = (off + nbytes + 255) & ~(size_t)255;
        return r;
    };
    half_t* Wh1  = (half_t*)alloc(294912 * 2);
    half_t* WTh1 = (half_t*)alloc(294912 * 2);
    half_t* Wh2  = (half_t*)alloc(589824 * 2);
    half_t* WTh2 = (half_t*)alloc(589824 * 2);
    half_t* Wsch = (half_t*)alloc(32768 * 2);
    float* bn1s = (float*)alloc(256 * 4);  float* bn1t = (float*)alloc(256 * 4);
    float* bn2s = (float*)alloc(256 * 4);  float* bn2t = (float*)alloc(256 * 4);
    float* bscs = (float*)alloc(256 * 4);  float* bsct = (float*)alloc(256 * 4);
    half_t* xTh  = (half_t*)alloc(NX * 2);   // aliased as r56h after shortcut+c0 consume it
    half_t* r56h = xTh;
    half_t* Pa   = (half_t*)alloc(NB * 2);
    half_t* Pb   = (half_t*)alloc(NB * 2);
    half_t* Pc   = (half_t*)alloc(NB * 2);
    half_t* Py   = (half_t*)alloc(NB * 2);
    half_t* r28h = (half_t*)alloc(NB * 2);
    float*  scF  = (float*)alloc(NB * 4);
    if (off > ws_size) return;

    float* outp = (float*)d_out;

    double t = 1.0; float al[3];
    for (int i = 0; i < 3; ++i) {
        double tn = (1.0 + sqrt(1.0 + 4.0 * t * t)) / 2.0;
        al[i] = (float)((t - 1.0) / tn); t = tn;
    }

    const dim3 blk(256);
    const dim3 gF(7, 2, 32);
    const dim3 gT2(28, 1, 32);
    const int n8 = (int)(NB / 8);
    const dim3 gC((n8 + 255) / 256);
    const float* NF = nullptr;
    const half_t* NH = nullptr;
    float* NFo = nullptr;
    half_t* NHo = nullptr;

    pack_w<9><<<256, blk, 0, stream>>>(W1, Wh1, WTh1, 128, 256, 1);
    pack_w<9><<<256, blk, 0, stream>>>(W2, Wh2, WTh2, 256, 256, 1);
    pack_w<1><<<256, blk, 0, stream>>>(Wsc, Wsch, nullptr, 128, 256, 0);
    bn_prep_kernel<<<1, blk, 0, stream>>>(bn1g, bn1b, bn1m, bn1v, bn1s, bn1t, 256);
    bn_prep_kernel<<<1, blk, 0, stream>>>(bn2g, bn2b, bn2m, bn2v, bn2s, bn2t, 256);
    bn_prep_kernel<<<1, blk, 0, stream>>>(bscg, bscb, bscm, bscv, bscs, bsct, 256);
    tx_kernel<<<dim3(56, 32), blk, 0, stream>>>(x, xTh);

    // ================= Stage A: dict_conv(x, W1, stride 2) =================
    conv_big<3,2,1,0><<<gF, blk, 0, stream>>>(Wh1, xTh, NFo, Pa, NH, NF,
        128, 256, 56, 56, 28, 28, 7, MU_F, 0.f, -SHRINK_F, 1, NF, NF, NF, 0);
    conv_big<1,2,0,0><<<gF, blk, 0, stream>>>(Wsch, xTh, scF, NHo, NH, NF,
        128, 256, 56, 56, 28, 28, 7, 1.f, 0.f, 0.f, 0, bscs, bsct, NF, 0);

    conv_big<3,2,1,2><<<gT2, blk, 0, stream>>>(WTh1, Pa, NFo, r56h, NH, x,
        256, 128, 28, 28, 56, 56, 7, -1.f, 1.f, 0.f, 0, NF, NF, NF, 0);
    conv_big<3,2,1,0><<<gF, blk, 0, stream>>>(Wh1, r56h, NFo, Pb, Pa, NF,
        128, 256, 56, 56, 28, 28, 7, MU_F, 1.f, -SHRINK_F, 1, NF, NF, NF, 0);

    comb_kernel<<<gC, blk, 0, stream>>>(Pb, Pa, Pc, 1.f + al[1], -al[1], n8);
    conv_big<3,2,1,2><<<gT2, blk, 0, stream>>>(WTh1, Pc, NFo, r56h, NH, x,
        256, 128, 28, 28, 56, 56, 7, -1.f, 1.f, 0.f, 0, NF, NF, NF, 0);
    conv_big<3,2,1,0><<<gF, blk, 0, stream>>>(Wh1, r56h, NFo, Pa, Pc, NF,
        128, 256, 56, 56, 28, 28, 7, MU_F, 1.f, -SHRINK_F, 1, NF, NF, NF, 0);

    comb_kernel<<<gC, blk, 0, stream>>>(Pa, Pb, Pc, 1.f + al[2], -al[2], n8);
    conv_big<3,2,1,2><<<gT2, blk, 0, stream>>>(WTh1, Pc, NFo, r56h, NH, x,
        256, 128, 28, 28, 56, 56, 7, -1.f, 1.f, 0.f, 0, NF, NF, NF, 0);
    conv_big<3,2,1,0><<<gF, blk, 0, stream>>>(Wh1, r56h, NFo, Py, Pc, NF,
        128, 256, 56, 56, 28, 28, 7, MU_F, 1.f, -SHRINK_F, 1, bn1s, bn1t, NF, 0);

    // ================= Stage B: dict_conv(y1, W2, stride 1) ================
    conv_big<3,1,1,0><<<gF, blk, 0, stream>>>(Wh2, Py, NFo, Pa, NH, NF,
        256, 256, 28, 28, 28, 28, 7, MU_F, 0.f, -SHRINK_F, 1, NF, NF, NF, 0);

    conv_big<3,1,1,1><<<gF, blk, 0, stream>>>(WTh2, Pa, NFo, r28h, Py, NF,
        256, 256, 28, 28, 28, 28, 7, -1.f, 1.f, 0.f, 0, NF, NF, NF, 0);
    conv_big<3,1,1,0><<<gF, blk, 0, stream>>>(Wh2, r28h, NFo, Pb, Pa, NF,
        256, 256, 28, 28, 28, 28, 7, MU_F, 1.f, -SHRINK_F, 1, NF, NF, NF, 0);

    comb_kernel<<<gC, blk, 0, stream>>>(Pb, Pa, Pc, 1.f + al[1], -al[1], n8);
    conv_big<3,1,1,1><<<gF, blk, 0, stream>>>(WTh2, Pc, NFo, r28h, Py, NF,
        256, 256, 28, 28, 28, 28, 7, -1.f, 1.f, 0.f, 0, NF, NF, NF, 0);
    conv_big<3,1,1,0><<<gF, blk, 0, stream>>>(Wh2, r28h, NFo, Pa, Pc, NF,
        256, 256, 28, 28, 28, 28, 7, MU_F, 1.f, -SHRINK_F, 1, NF, NF, NF, 0);

    comb_kernel<<<gC, blk, 0, stream>>>(Pa, Pb, Pc, 1.f + al[2], -al[2], n8);
    conv_big<3,1,1,1><<<gF, blk, 0, stream>>>(WTh2, Pc, NFo, r28h, Py, NF,
        256, 256, 28, 28, 28, 28, 7, -1.f, 1.f, 0.f, 0, NF, NF, NF, 0);
    conv_big<3,1,1,0><<<gF, blk, 0, stream>>>(Wh2, r28h, outp, NHo, Pc, NF,
        256, 256, 28, 28, 28, 28, 7, MU_F, 1.f, -SHRINK_F, 1, bn2s, bn2t, scF, 1);
}